// Round 9
// baseline (114.229 us; speedup 1.0000x reference)
//
#include <hip/hip_runtime.h>
#include <hip/hip_fp16.h>
#include <cstdint>

namespace {

typedef _Float16 h2 __attribute__((ext_vector_type(2)));

constexpr int BATCH   = 8192;
constexpr int IN      = 64;
constexpr int U       = 128;
constexpr int UNFOLDS = 3;
constexpr float LOG2E = 1.4426950408889634f;

// split-pack geometry (A/B f32 from L2, W-packs in LDS, 2 blocks/CU)
constexpr int R    = 4;           // batches per thread
constexpr int NT   = 512;         // threads per block (8 waves)
constexpr int TB   = 16;          // batches per block (4 groups * R)
constexpr int PADV = 20;          // floats per LDS row
constexpr int SENP = (IN / 2) * U;   // 4096 sensory pairs
constexpr int RECP = (U / 2) * U;    // 8192 recurrent pairs

// ws layout (bytes)
constexpr size_t OFF_RAB = 0;                         // float4[RECP] 128K
constexpr size_t OFF_RW  = OFF_RAB + RECP * 16;       // uint2 [RECP]  64K
constexpr size_t OFF_SAB = OFF_RW  + RECP * 8;        // float4[SENP]  64K
constexpr size_t OFF_SW  = OFF_SAB + SENP * 16;       // uint2 [SENP]  32K
constexpr size_t WS_NEED = OFF_SW  + SENP * 8;        // 294912 B

// fallback geometry (verified R6 kernel, weights in LDS)
constexpr int FR   = 4;
constexpr int FNT  = 1024;
constexpr int FTB  = 32;
constexpr int FPAD = 36;

union HU { uint32_t u; h2 h; };

__device__ __forceinline__ uint32_t pack2(float lo, float hi) {
  __half l = __float2half_rn(lo);
  __half h = __float2half_rn(hi);
  return (uint32_t)__half_as_ushort(l) | ((uint32_t)__half_as_ushort(h) << 16);
}

// Gate pair with ONE rcp: sigma0 = a1*r, sigma1 = a0*r, r = rcp(a0*a1),
// a_k = 1 + 2^(A_k*v_k+B_k). Accumulate via packed f16 dot2.
__device__ __forceinline__ void gate2(float A0, float B0, float A1, float B1,
                                      h2 wpk, h2 wepk, float v0, float v1,
                                      float& num, float& den) {
  const float t0 = fmaf(A0, v0, B0);              // -log2e*sigma*(v-mu)
  const float t1 = fmaf(A1, v1, B1);
  const float e0 = __builtin_amdgcn_exp2f(t0);
  const float e1 = __builtin_amdgcn_exp2f(t1);
  const float a0 = 1.0f + e0;
  const float a1 = 1.0f + e1;
  const float r  = __builtin_amdgcn_rcpf(a0 * a1);
  const float rc0 = a1 * r;                       // sigmoid(x0)
  const float rc1 = a0 * r;                       // sigmoid(x1)
  const h2 rpk = __builtin_bit_cast(h2, __builtin_amdgcn_cvt_pkrtz(rc0, rc1));
  den = __builtin_amdgcn_fdot2(rpk, wpk,  den, false);  // += W0*rc0 + W1*rc1
  num = __builtin_amdgcn_fdot2(rpk, wepk, num, false);  // += We0*rc0 + We1*rc1
}

// ---- one-time prepack into d_ws: A/B as f32x4, W/We as f16x2 pairs ----
__global__ __launch_bounds__(256)
void prepack(const float* __restrict__ s_mu, const float* __restrict__ s_sigma,
             const float* __restrict__ s_W, const float* __restrict__ s_erev,
             const float* __restrict__ r_mu, const float* __restrict__ r_sigma,
             const float* __restrict__ r_W, const float* __restrict__ r_erev,
             uint8_t* __restrict__ ws)
{
  float4* rab = (float4*)(ws + OFF_RAB);
  uint2*  rw  = (uint2*) (ws + OFF_RW);
  float4* sab = (float4*)(ws + OFF_SAB);
  uint2*  sw  = (uint2*) (ws + OFF_SW);

  const int k = blockIdx.x * 256 + threadIdx.x;
  if (k < SENP) {
    const int p = k >> 7, uu = k & (U - 1);
    const int i0 = 2 * p, i1 = i0 + 1;
    const float sg0 = s_sigma[i0 * U + uu], sg1 = s_sigma[i1 * U + uu];
    const float w0  = s_W[i0 * U + uu],     w1  = s_W[i1 * U + uu];
    sab[k] = make_float4(-LOG2E * sg0, LOG2E * sg0 * s_mu[i0 * U + uu],
                         -LOG2E * sg1, LOG2E * sg1 * s_mu[i1 * U + uu]);
    uint2 q;
    q.x = pack2(w0, w1);
    q.y = pack2(w0 * s_erev[i0 * U + uu], w1 * s_erev[i1 * U + uu]);
    sw[k] = q;
  } else if (k < SENP + RECP) {
    const int kk = k - SENP;
    const int p = kk >> 7, uu = kk & (U - 1);
    const int i0 = 2 * p, i1 = i0 + 1;
    const float sg0 = r_sigma[i0 * U + uu], sg1 = r_sigma[i1 * U + uu];
    const float w0  = r_W[i0 * U + uu],     w1  = r_W[i1 * U + uu];
    rab[kk] = make_float4(-LOG2E * sg0, LOG2E * sg0 * r_mu[i0 * U + uu],
                          -LOG2E * sg1, LOG2E * sg1 * r_mu[i1 * U + uu]);
    uint2 q;
    q.x = pack2(w0, w1);
    q.y = pack2(w0 * r_erev[i0 * U + uu], w1 * r_erev[i1 * U + uu]);
    rw[kk] = q;
  }
}

// ---- main: A/B f32 from L2 (no decode cvts), W-packs in LDS, 2 blocks/CU ----
__global__ __launch_bounds__(NT, 4)
void ltc_split(const uint8_t* __restrict__ ws,
               const float* __restrict__ inputs, const float* __restrict__ state,
               const float* __restrict__ vleak, const float* __restrict__ gleak,
               const float* __restrict__ cm_t, float* __restrict__ out)
{
  const float4* rab = (const float4*)(ws + OFF_RAB);
  const uint2*  rw  = (const uint2*) (ws + OFF_RW);
  const float4* sab = (const float4*)(ws + OFF_SAB);
  const uint2*  sw  = (const uint2*) (ws + OFF_SW);

  __shared__ uint2 wpack_s[RECP];       // 64 KB recurrent W/We packs
  __shared__ float vp_s[U][PADV];       // 10 KB v_pre, [presyn i][b_local]
  __shared__ float inp_s[IN][PADV];     // 5 KB inputs, [i][b_local]

  const int tid = threadIdx.x;
  const int u   = tid & (U - 1);
  const int bl  = tid >> 7;             // 0..3
  const int b0  = blockIdx.x * TB;

  const float cm   = cm_t[u];
  const float gl   = gleak[u];
  const float numc = gl * vleak[u];
  const float denc = cm + gl + 1e-8f;

  // stage recurrent W-packs into LDS (coalesced dwordx2)
  for (int k = tid; k < RECP; k += NT) wpack_s[k] = rw[k];
  // stage inputs transposed: inp_s[i][b_local]
  for (int k = tid; k < TB * IN; k += NT) {
    inp_s[k & (IN - 1)][k >> 6] = inputs[b0 * IN + k];
  }
  // stage state transposed: vp_s[i][b_local]
  for (int k = tid; k < TB * U; k += NT) {
    vp_s[k & (U - 1)][k >> 7] = state[b0 * U + k];
  }
  float vo[R];
#pragma unroll
  for (int r = 0; r < R; ++r) vo[r] = state[(b0 + bl * R + r) * U + u];
  __syncthreads();

  // sensory reduction (32 pairs), A/B + W from L2
  float num_s[R], den_s[R];
#pragma unroll
  for (int r = 0; r < R; ++r) { num_s[r] = 0.f; den_s[r] = 0.f; }
#pragma unroll 4
  for (int p = 0; p < IN / 2; ++p) {
    const float4 ab = sab[p * U + u];
    const uint2  wz = sw[p * U + u];
    const float4 va = *reinterpret_cast<const float4*>(&inp_s[2 * p][bl * R]);
    const float4 vb = *reinterpret_cast<const float4*>(&inp_s[2 * p + 1][bl * R]);
    HU z, w; z.u = wz.x; w.u = wz.y;
#pragma unroll
    for (int r = 0; r < R; ++r)
      gate2(ab.x, ab.y, ab.z, ab.w, z.h, w.h, (&va.x)[r], (&vb.x)[r], num_s[r], den_s[r]);
  }

  // 3 unfolds (64 pairs each): A/B from L2, W-packs from LDS
#pragma unroll
  for (int t = 0; t < UNFOLDS; ++t) {
    float num[R], den[R];
#pragma unroll
    for (int r = 0; r < R; ++r) { num[r] = num_s[r]; den[r] = den_s[r]; }
#pragma unroll 4
    for (int p = 0; p < U / 2; ++p) {
      const float4 ab = rab[p * U + u];
      const uint2  wz = wpack_s[p * U + u];
      const float4 va = *reinterpret_cast<const float4*>(&vp_s[2 * p][bl * R]);
      const float4 vb = *reinterpret_cast<const float4*>(&vp_s[2 * p + 1][bl * R]);
      HU z, w; z.u = wz.x; w.u = wz.y;
#pragma unroll
      for (int r = 0; r < R; ++r)
        gate2(ab.x, ab.y, ab.z, ab.w, z.h, w.h, (&va.x)[r], (&vb.x)[r], num[r], den[r]);
    }
    float vnew[R];
#pragma unroll
    for (int r = 0; r < R; ++r) {
      vnew[r] = (fmaf(cm, vo[r], numc) + num[r]) * __builtin_amdgcn_rcpf(denc + den[r]);
      vo[r] = vnew[r];
    }
    if (t == UNFOLDS - 1) {
#pragma unroll
      for (int r = 0; r < R; ++r) out[(b0 + bl * R + r) * U + u] = vnew[r];
    } else {
      __syncthreads();
      *reinterpret_cast<float4*>(&vp_s[u][bl * R]) =
          make_float4(vnew[0], vnew[1], vnew[2], vnew[3]);
      __syncthreads();
    }
  }
}

// ---- fallback: verified R6 kernel (weights in LDS), used if ws too small ----
__global__ __launch_bounds__(FNT, 4)
void ltc_fused(const float* __restrict__ inputs, const float* __restrict__ state,
               const float* __restrict__ s_mu, const float* __restrict__ s_sigma,
               const float* __restrict__ s_W, const float* __restrict__ s_erev,
               const float* __restrict__ r_mu, const float* __restrict__ r_sigma,
               const float* __restrict__ r_W, const float* __restrict__ r_erev,
               const float* __restrict__ vleak, const float* __restrict__ gleak,
               const float* __restrict__ cm_t, float* __restrict__ out)
{
  __shared__ uint4 pack_s[(U / 2) * U];
  __shared__ float vp_s[U][FPAD];
  __shared__ float inp_s[IN][FPAD];

  const int tid = threadIdx.x;
  const int u   = tid & (U - 1);
  const int bl  = tid >> 7;
  const int b0  = blockIdx.x * FTB;

  const float cm   = cm_t[u];
  const float gl   = gleak[u];
  const float numc = gl * vleak[u];
  const float denc = cm + gl + 1e-8f;

  for (int k = tid; k < (IN / 2) * U; k += FNT) {
    const int p  = k >> 7;
    const int uu = k & (U - 1);
    const int i0 = 2 * p, i1 = i0 + 1;
    const float sg0 = s_sigma[i0 * U + uu], sg1 = s_sigma[i1 * U + uu];
    const float w0  = s_W[i0 * U + uu],     w1  = s_W[i1 * U + uu];
    uint4 q;
    q.x = pack2(-LOG2E * sg0, LOG2E * sg0 * s_mu[i0 * U + uu]);
    q.y = pack2(-LOG2E * sg1, LOG2E * sg1 * s_mu[i1 * U + uu]);
    q.z = pack2(w0, w1);
    q.w = pack2(w0 * s_erev[i0 * U + uu], w1 * s_erev[i1 * U + uu]);
    pack_s[k] = q;
  }
  for (int k = tid; k < FTB * IN; k += FNT) {
    inp_s[k & (IN - 1)][k >> 6] = inputs[b0 * IN + k];
  }
  for (int k = tid; k < FTB * U; k += FNT) {
    vp_s[k & (U - 1)][k >> 7] = state[b0 * U + k];
  }
  float vo[FR];
#pragma unroll
  for (int r = 0; r < FR; ++r) vo[r] = state[(b0 + bl * FR + r) * U + u];
  __syncthreads();

  float num_s[FR], den_s[FR];
#pragma unroll
  for (int r = 0; r < FR; ++r) { num_s[r] = 0.f; den_s[r] = 0.f; }
#pragma unroll 4
  for (int p = 0; p < IN / 2; ++p) {
    const uint4 q = pack_s[p * U + u];
    const float4 va = *reinterpret_cast<const float4*>(&inp_s[2 * p][bl * FR]);
    const float4 vb = *reinterpret_cast<const float4*>(&inp_s[2 * p + 1][bl * FR]);
    HU x, y, z, w; x.u = q.x; y.u = q.y; z.u = q.z; w.u = q.w;
    const float A0 = (float)x.h.x, B0 = (float)x.h.y;
    const float A1 = (float)y.h.x, B1 = (float)y.h.y;
#pragma unroll
    for (int r = 0; r < FR; ++r)
      gate2(A0, B0, A1, B1, z.h, w.h, (&va.x)[r], (&vb.x)[r], num_s[r], den_s[r]);
  }
  __syncthreads();

  for (int k = tid; k < (U / 2) * U; k += FNT) {
    const int p  = k >> 7;
    const int uu = k & (U - 1);
    const int i0 = 2 * p, i1 = i0 + 1;
    const float sg0 = r_sigma[i0 * U + uu], sg1 = r_sigma[i1 * U + uu];
    const float w0  = r_W[i0 * U + uu],     w1  = r_W[i1 * U + uu];
    uint4 q;
    q.x = pack2(-LOG2E * sg0, LOG2E * sg0 * r_mu[i0 * U + uu]);
    q.y = pack2(-LOG2E * sg1, LOG2E * sg1 * r_mu[i1 * U + uu]);
    q.z = pack2(w0, w1);
    q.w = pack2(w0 * r_erev[i0 * U + uu], w1 * r_erev[i1 * U + uu]);
    pack_s[k] = q;
  }
  __syncthreads();

#pragma unroll
  for (int t = 0; t < UNFOLDS; ++t) {
    float num[FR], den[FR];
#pragma unroll
    for (int r = 0; r < FR; ++r) { num[r] = num_s[r]; den[r] = den_s[r]; }
#pragma unroll 4
    for (int p = 0; p < U / 2; ++p) {
      const uint4 q = pack_s[p * U + u];
      const float4 va = *reinterpret_cast<const float4*>(&vp_s[2 * p][bl * FR]);
      const float4 vb = *reinterpret_cast<const float4*>(&vp_s[2 * p + 1][bl * FR]);
      HU x, y, z, w; x.u = q.x; y.u = q.y; z.u = q.z; w.u = q.w;
      const float A0 = (float)x.h.x, B0 = (float)x.h.y;
      const float A1 = (float)y.h.x, B1 = (float)y.h.y;
#pragma unroll
      for (int r = 0; r < FR; ++r)
        gate2(A0, B0, A1, B1, z.h, w.h, (&va.x)[r], (&vb.x)[r], num[r], den[r]);
    }
    float vnew[FR];
#pragma unroll
    for (int r = 0; r < FR; ++r) {
      vnew[r] = (fmaf(cm, vo[r], numc) + num[r]) * __builtin_amdgcn_rcpf(denc + den[r]);
      vo[r] = vnew[r];
    }
    if (t == UNFOLDS - 1) {
#pragma unroll
      for (int r = 0; r < FR; ++r) out[(b0 + bl * FR + r) * U + u] = vnew[r];
    } else {
      __syncthreads();
      *reinterpret_cast<float4*>(&vp_s[u][bl * FR]) =
          make_float4(vnew[0], vnew[1], vnew[2], vnew[3]);
      __syncthreads();
    }
  }
}

} // namespace

extern "C" void kernel_launch(void* const* d_in, const int* in_sizes, int n_in,
                              void* d_out, int out_size, void* d_ws, size_t ws_size,
                              hipStream_t stream) {
  const float* inputs   = (const float*)d_in[0];
  const float* state    = (const float*)d_in[1];
  const float* s_mu     = (const float*)d_in[2];
  const float* s_sigma  = (const float*)d_in[3];
  const float* s_W      = (const float*)d_in[4];
  const float* s_erev   = (const float*)d_in[5];
  const float* r_mu     = (const float*)d_in[6];
  const float* r_sigma  = (const float*)d_in[7];
  const float* r_W      = (const float*)d_in[8];
  const float* r_erev   = (const float*)d_in[9];
  const float* vleak    = (const float*)d_in[10];
  const float* gleak    = (const float*)d_in[11];
  const float* cm_t     = (const float*)d_in[12];
  float* out = (float*)d_out;

  if (ws_size >= WS_NEED) {
    uint8_t* ws = (uint8_t*)d_ws;
    prepack<<<dim3((SENP + RECP + 255) / 256), dim3(256), 0, stream>>>(
        s_mu, s_sigma, s_W, s_erev, r_mu, r_sigma, r_W, r_erev, ws);
    ltc_split<<<dim3(BATCH / TB), dim3(NT), 0, stream>>>(
        ws, inputs, state, vleak, gleak, cm_t, out);
  } else {
    ltc_fused<<<dim3(BATCH / FTB), dim3(FNT), 0, stream>>>(
        inputs, state, s_mu, s_sigma, s_W, s_erev,
        r_mu, r_sigma, r_W, r_erev, vleak, gleak, cm_t, out);
  }
}

// Round 10
// 108.815 us; speedup vs baseline: 1.0498x; 1.0498x over previous
//
#include <hip/hip_runtime.h>
#include <hip/hip_fp16.h>
#include <cstdint>

namespace {

typedef _Float16 h2 __attribute__((ext_vector_type(2)));

constexpr int BATCH   = 8192;
constexpr int IN      = 64;
constexpr int U       = 128;
constexpr int R       = 4;        // batches per thread
constexpr int TB      = 32;       // batches per block
constexpr int NT      = 1024;     // threads per block (16 waves)
constexpr int UNFOLDS = 3;
constexpr int PAD     = 36;       // floats per LDS row
constexpr float LOG2E = 1.4426950408889634f;

union HU { uint32_t u; h2 h; };

__device__ __forceinline__ uint32_t pack2(float lo, float hi) {
  __half l = __float2half_rn(lo);
  __half h = __float2half_rn(hi);
  return (uint32_t)__half_as_ushort(l) | ((uint32_t)__half_as_ushort(h) << 16);
}

// Gate pair with ONE rcp: sigma0 = a1*r, sigma1 = a0*r, r = rcp(a0*a1),
// a_k = 1 + 2^(A_k*v_k+B_k). Accumulate via packed f16 dot2.
// (pair-rcp is the optimal sharing level: marginal cost 3 muls (6cy) < rcp (8cy);
//  quad-level sharing costs 7 muls (14cy) > 8cy — measured & counted, R5->R6.)
__device__ __forceinline__ void gate2(float A0, float B0, float A1, float B1,
                                      h2 wpk, h2 wepk, float v0, float v1,
                                      float& num, float& den) {
  const float t0 = fmaf(A0, v0, B0);              // -log2e*sigma*(v-mu)
  const float t1 = fmaf(A1, v1, B1);
  const float e0 = __builtin_amdgcn_exp2f(t0);
  const float e1 = __builtin_amdgcn_exp2f(t1);
  const float a0 = 1.0f + e0;
  const float a1 = 1.0f + e1;
  const float r  = __builtin_amdgcn_rcpf(a0 * a1);
  const float rc0 = a1 * r;                       // sigmoid(x0)
  const float rc1 = a0 * r;                       // sigmoid(x1)
  const h2 rpk = __builtin_bit_cast(h2, __builtin_amdgcn_cvt_pkrtz(rc0, rc1));
  den = __builtin_amdgcn_fdot2(rpk, wpk,  den, false);  // += W0*rc0 + W1*rc1
  num = __builtin_amdgcn_fdot2(rpk, wepk, num, false);  // += We0*rc0 + We1*rc1
}

__global__ __launch_bounds__(NT, 4)
void ltc_fused(const float* __restrict__ inputs, const float* __restrict__ state,
               const float* __restrict__ s_mu, const float* __restrict__ s_sigma,
               const float* __restrict__ s_W, const float* __restrict__ s_erev,
               const float* __restrict__ r_mu, const float* __restrict__ r_sigma,
               const float* __restrict__ r_W, const float* __restrict__ r_erev,
               const float* __restrict__ vleak, const float* __restrict__ gleak,
               const float* __restrict__ cm_t, float* __restrict__ out)
{
  __shared__ uint4 pack_s[(U / 2) * U];   // 128 KB recurrent packs (sensory reuses 64 KB)
  __shared__ float vp_s[U][PAD];          // v_pre, [presyn i][b_local]
  __shared__ float inp_s[IN][PAD];        // inputs, [i][b_local]

  const int tid = threadIdx.x;
  const int u   = tid & (U - 1);
  const int bl  = tid >> 7;
  const int b0  = blockIdx.x * TB;

  const float cm   = cm_t[u];
  const float gl   = gleak[u];
  const float numc = gl * vleak[u];
  const float denc = cm + gl + 1e-8f;

  // ---- stage sensory packs (i-pair interleaved) ----
  for (int k = tid; k < (IN / 2) * U; k += NT) {
    const int p  = k >> 7;
    const int uu = k & (U - 1);
    const int i0 = 2 * p, i1 = i0 + 1;
    const float sg0 = s_sigma[i0 * U + uu], sg1 = s_sigma[i1 * U + uu];
    const float w0  = s_W[i0 * U + uu],     w1  = s_W[i1 * U + uu];
    uint4 q;
    q.x = pack2(-LOG2E * sg0, LOG2E * sg0 * s_mu[i0 * U + uu]);
    q.y = pack2(-LOG2E * sg1, LOG2E * sg1 * s_mu[i1 * U + uu]);
    q.z = pack2(w0, w1);
    q.w = pack2(w0 * s_erev[i0 * U + uu], w1 * s_erev[i1 * U + uu]);
    pack_s[k] = q;
  }
  for (int k = tid; k < TB * IN; k += NT) {
    inp_s[k & (IN - 1)][k >> 6] = inputs[b0 * IN + k];
  }
  for (int k = tid; k < TB * U; k += NT) {
    vp_s[k & (U - 1)][k >> 7] = state[b0 * U + k];
  }
  float vo[R];
#pragma unroll
  for (int r = 0; r < R; ++r) vo[r] = state[(b0 + bl * R + r) * U + u];
  __syncthreads();

  // ---- sensory reduction over IN (32 pairs) ----
  float num_s[R], den_s[R];
#pragma unroll
  for (int r = 0; r < R; ++r) { num_s[r] = 0.f; den_s[r] = 0.f; }
#pragma unroll 4
  for (int p = 0; p < IN / 2; ++p) {
    const uint4 q = pack_s[p * U + u];
    const float4 va = *reinterpret_cast<const float4*>(&inp_s[2 * p][bl * R]);
    const float4 vb = *reinterpret_cast<const float4*>(&inp_s[2 * p + 1][bl * R]);
    HU x, y, z, w; x.u = q.x; y.u = q.y; z.u = q.z; w.u = q.w;
    const float A0 = (float)x.h.x, B0 = (float)x.h.y;
    const float A1 = (float)y.h.x, B1 = (float)y.h.y;
#pragma unroll
    for (int r = 0; r < R; ++r)
      gate2(A0, B0, A1, B1, z.h, w.h, (&va.x)[r], (&vb.x)[r], num_s[r], den_s[r]);
  }
  __syncthreads();  // sensory region reads done

  // ---- stage recurrent packs (overwrites sensory region) ----
  for (int k = tid; k < (U / 2) * U; k += NT) {
    const int p  = k >> 7;
    const int uu = k & (U - 1);
    const int i0 = 2 * p, i1 = i0 + 1;
    const float sg0 = r_sigma[i0 * U + uu], sg1 = r_sigma[i1 * U + uu];
    const float w0  = r_W[i0 * U + uu],     w1  = r_W[i1 * U + uu];
    uint4 q;
    q.x = pack2(-LOG2E * sg0, LOG2E * sg0 * r_mu[i0 * U + uu]);
    q.y = pack2(-LOG2E * sg1, LOG2E * sg1 * r_mu[i1 * U + uu]);
    q.z = pack2(w0, w1);
    q.w = pack2(w0 * r_erev[i0 * U + uu], w1 * r_erev[i1 * U + uu]);
    pack_s[k] = q;
  }
  __syncthreads();

  // ---- 3 unfolds (64 pairs each) ----
#pragma unroll
  for (int t = 0; t < UNFOLDS; ++t) {
    float num[R], den[R];
#pragma unroll
    for (int r = 0; r < R; ++r) { num[r] = num_s[r]; den[r] = den_s[r]; }
#pragma unroll 4
    for (int p = 0; p < U / 2; ++p) {
      const uint4 q = pack_s[p * U + u];
      const float4 va = *reinterpret_cast<const float4*>(&vp_s[2 * p][bl * R]);
      const float4 vb = *reinterpret_cast<const float4*>(&vp_s[2 * p + 1][bl * R]);
      HU x, y, z, w; x.u = q.x; y.u = q.y; z.u = q.z; w.u = q.w;
      const float A0 = (float)x.h.x, B0 = (float)x.h.y;
      const float A1 = (float)y.h.x, B1 = (float)y.h.y;
#pragma unroll
      for (int r = 0; r < R; ++r)
        gate2(A0, B0, A1, B1, z.h, w.h, (&va.x)[r], (&vb.x)[r], num[r], den[r]);
    }
    float vnew[R];
#pragma unroll
    for (int r = 0; r < R; ++r) {
      vnew[r] = (fmaf(cm, vo[r], numc) + num[r]) * __builtin_amdgcn_rcpf(denc + den[r]);
      vo[r] = vnew[r];
    }
    if (t == UNFOLDS - 1) {
#pragma unroll
      for (int r = 0; r < R; ++r) out[(b0 + bl * R + r) * U + u] = vnew[r];
    } else {
      __syncthreads();
      *reinterpret_cast<float4*>(&vp_s[u][bl * R]) =
          make_float4(vnew[0], vnew[1], vnew[2], vnew[3]);
      __syncthreads();
    }
  }
}

} // namespace

extern "C" void kernel_launch(void* const* d_in, const int* in_sizes, int n_in,
                              void* d_out, int out_size, void* d_ws, size_t ws_size,
                              hipStream_t stream) {
  const float* inputs   = (const float*)d_in[0];
  const float* state    = (const float*)d_in[1];
  const float* s_mu     = (const float*)d_in[2];
  const float* s_sigma  = (const float*)d_in[3];
  const float* s_W      = (const float*)d_in[4];
  const float* s_erev   = (const float*)d_in[5];
  const float* r_mu     = (const float*)d_in[6];
  const float* r_sigma  = (const float*)d_in[7];
  const float* r_W      = (const float*)d_in[8];
  const float* r_erev   = (const float*)d_in[9];
  const float* vleak    = (const float*)d_in[10];
  const float* gleak    = (const float*)d_in[11];
  const float* cm_t     = (const float*)d_in[12];
  float* out = (float*)d_out;

  ltc_fused<<<dim3(BATCH / TB), dim3(NT), 0, stream>>>(
      inputs, state, s_mu, s_sigma, s_W, s_erev,
      r_mu, r_sigma, r_W, r_erev, vleak, gleak, cm_t, out);
}